// Round 7
// baseline (8185.473 us; speedup 1.0000x reference)
//
#include <hip/hip_runtime.h>
#include <math.h>

// Problem constants (Elman RNN)
#define TT 4096
#define HH 2048
#define OO 512

#define NB  128    // scan blocks
#define RPB 16     // rows per block = HH/NB
#define MBW (HH/2) // mailbox words per buffer (fp16 x2 per word)

#define CHUNK_T 64             // t-rows per xp chunk
#define NCHUNK  (TT/CHUNK_T)   // 64 chunks
#define HTILE   128
#define NHT     (HH/HTILE)     // 16 h-tiles per chunk

typedef __fp16 half2v __attribute__((ext_vector_type(2)));

// ---------------------------------------------------------------------------
// Trailing phase 3: fp32 NT GEMM  C[m,n] = sum_k A[m,k]*B[n,k] + bias[n]
// 64x64 tiles, 512 blocks, 256 threads, 4x4 acc/thread, BK=8.
// ---------------------------------------------------------------------------
__global__ __launch_bounds__(256) void gemm_nt_bias64(
    const float* __restrict__ A, const float* __restrict__ B,
    const float* __restrict__ bias, float* __restrict__ C,
    int M, int N, int K)
{
    __shared__ float As[8][72];
    __shared__ float Bs[8][72];

    const int tid = threadIdx.x;
    const int bm = blockIdx.x * 64;
    const int bn = blockIdx.y * 64;

    const int srow = tid >> 2;          // 0..63
    const int skk  = (tid & 3) * 2;     // 0,2,4,6

    const int ty = tid >> 4;            // 0..15
    const int tx = tid & 15;            // 0..15

    float acc[4][4];
#pragma unroll
    for (int i = 0; i < 4; i++)
#pragma unroll
        for (int j = 0; j < 4; j++) acc[i][j] = 0.f;

    for (int k0 = 0; k0 < K; k0 += 8) {
        float2 av = *(const float2*)&A[(size_t)(bm + srow) * K + k0 + skk];
        float2 bv = *(const float2*)&B[(size_t)(bn + srow) * K + k0 + skk];
        __syncthreads();
        As[skk][srow]     = av.x;
        As[skk + 1][srow] = av.y;
        Bs[skk][srow]     = bv.x;
        Bs[skk + 1][srow] = bv.y;
        __syncthreads();
#pragma unroll
        for (int kk = 0; kk < 8; kk++) {
            float4 a4 = *(const float4*)&As[kk][ty * 4];
            float4 b4 = *(const float4*)&Bs[kk][tx * 4];
            float a[4] = {a4.x, a4.y, a4.z, a4.w};
            float b[4] = {b4.x, b4.y, b4.z, b4.w};
#pragma unroll
            for (int i = 0; i < 4; i++)
#pragma unroll
                for (int j = 0; j < 4; j++)
                    acc[i][j] += a[i] * b[j];
        }
    }

    {
        const int n = bn + tx * 4;
        float4 bv = *(const float4*)&bias[n];
#pragma unroll
        for (int i = 0; i < 4; i++) {
            const int m = bm + ty * 4 + i;
            float4 cv;
            cv.x = acc[i][0] + bv.x;
            cv.y = acc[i][1] + bv.y;
            cv.z = acc[i][2] + bv.z;
            cv.w = acc[i][3] + bv.w;
            *(float4*)&C[(size_t)m * N + n] = cv;
        }
    }
}

// ---------------------------------------------------------------------------
// R22 fused kernel: EXACT R20 core (topology reverted from R21's failed
// 64x32 -- +640 cyc/step from 128 extra clustered LDS instrs/CU) + ONE
// change: the simple agent-scope poll do-while is replaced by a PIPELINED
// TAG SAMPLER (counted-vmcnt rolling poll, T4 applied to spin-waiting).
//   Why: the simple do-while samples every ~RT (~900 cyc) because each
//   load's return gates the next issue. Late-arrival steps pay a full-RT
//   quantization penalty (R20's sleep-gradient data fits this).
//   How: inline-asm ring of 3 sample-pairs {4B tag probe at addr+4, 8B
//   full word}, issues spread by s_sleep(2)~128cyc; s_waitcnt vmcnt(4)
//   checks the oldest pair while 2 pairs remain in flight -> sampling
//   period ~900 -> ~130 cyc, first-check latency unchanged.
//   Safety: (1) tag issued BEFORE full word -> a matching tag validates
//   the younger full sample (tags are monotonic within the window: a word
//   flips old->want once and stays until t+2); (2) ring bounded at 16
//   cycles then ph=3 -> fall back to the UNCHANGED C++ atomic do-while,
//   which re-validates the embedded tag -- any flag/semantic surprise can
//   only cause retries, never wrong data; (3) ring regs are loop-carried
//   ("+v") and consumed after the loop, so in-flight returns always land
//   in live registers; (4) wave0's xp load is asm-issued BEFORE the ring
//   (FIFO-oldest) and the tail's s_waitcnt vmcnt(4) provably completes it
//   (if >4 outstanding, the oldest completed; if <=4, FIFO says it
//   already returned) without draining the ring.
// Iron rule (R2/R12/R13): during the live exchange every other CU is DEAD.
// Gating invariant: wave0's publish of step t data-depends on ALL 16
// partials of step t (unchanged).
// ---------------------------------------------------------------------------
__global__ __launch_bounds__(1024) void rnn_fused(
    const float* __restrict__ x,     // (T,H) input
    const float* __restrict__ Wih,   // (H,H)
    const float* __restrict__ bih,   // (H)
    const float* __restrict__ Whh,   // (H,H)
    const float* __restrict__ bhh,   // (H)
    const float* __restrict__ h0,    // (H)
    float* __restrict__ xp,          // (T,H) ws: input projection
    float* __restrict__ outs,        // (T,H) ws: hidden states
    unsigned long long* __restrict__ mbox,  // [2][MBW] tagged fp16x2 mailbox
    int* __restrict__ chunk_done)    // [NCHUNK] xp-chunk arm counters
{
    const int tid = threadIdx.x;     // 0..1023

    if (blockIdx.x >= NB) {
        // ------------------- xp GEMM worker (exact R10) -------------------
        __shared__ float As[16][65];     // [kk][t-row], padded
        __shared__ float Bs[16][132];    // [kk][h-col], padded+aligned

        const int w2   = blockIdx.x - NB;   // 0..127
        const int ty   = tid >> 5;          // 0..31
        const int tx   = tid & 31;          // 0..31
        const int arow = tid >> 4;          // 0..63
        const int akk  = tid & 15;
        const int bcol = tid >> 3;          // 0..127
        const int bkk  = (tid & 7) * 2;

        for (int round = 0; round < (NCHUNK * NHT) / 128; ++round) {
            const int tile  = w2 + 128 * round;   // t-major: early t first
            const int chunk = tile >> 4;
            const int htile = tile & 15;
            const int bm = chunk * CHUNK_T;
            const int bn = htile * HTILE;

            float acc[2][4];
#pragma unroll
            for (int i = 0; i < 2; ++i)
#pragma unroll
                for (int j = 0; j < 4; ++j) acc[i][j] = 0.f;

            for (int k0 = 0; k0 < HH; k0 += 16) {
                float  av = x[(size_t)(bm + arow) * HH + k0 + akk];
                float2 bv = *(const float2*)&Wih[(size_t)(bn + bcol) * HH + k0 + bkk];
                __syncthreads();
                As[akk][arow]     = av;
                Bs[bkk][bcol]     = bv.x;
                Bs[bkk + 1][bcol] = bv.y;
                __syncthreads();
#pragma unroll
                for (int kk = 0; kk < 16; ++kk) {
                    float a0 = As[kk][ty * 2];
                    float a1 = As[kk][ty * 2 + 1];
                    float b0 = Bs[kk][tx * 4 + 0];
                    float b1 = Bs[kk][tx * 4 + 1];
                    float b2 = Bs[kk][tx * 4 + 2];
                    float b3 = Bs[kk][tx * 4 + 3];
                    acc[0][0] += a0 * b0; acc[0][1] += a0 * b1;
                    acc[0][2] += a0 * b2; acc[0][3] += a0 * b3;
                    acc[1][0] += a1 * b0; acc[1][1] += a1 * b1;
                    acc[1][2] += a1 * b2; acc[1][3] += a1 * b3;
                }
            }
#pragma unroll
            for (int i = 0; i < 2; ++i) {
                const int m = bm + ty * 2 + i;
#pragma unroll
                for (int j = 0; j < 4; ++j) {
                    const int n = bn + tx * 4 + j;
                    __hip_atomic_store(&xp[(size_t)m * HH + n],
                                       acc[i][j] + bih[n],
                                       __ATOMIC_RELAXED, __HIP_MEMORY_SCOPE_AGENT);
                }
            }
            __syncthreads();   // all waves' stores retired first
            if (tid == 0)
                __hip_atomic_fetch_add(&chunk_done[chunk], 1,
                                       __ATOMIC_RELEASE, __HIP_MEMORY_SCOPE_AGENT);
        }
        return;   // workers DIE here -- CUs go fully idle for the scan
    }

    // ------------- scan (R20 core + R22 pipelined tag sampler) -------------
    const int b    = blockIdx.x;     // 0..127
    const int wave = tid >> 6;       // 0..15
    const int lane = tid & 63;
    const int r    = lane & 15;      // local row 0..15
    const int q    = lane >> 4;      // 0..3: interleaved 4-float subchunk
    const int row  = b * RPB + r;    // global row this thread accumulates
    const int m0   = wave * 64 + lane;      // my mailbox word (covers 2 rows)
    const int s0   = wave * 128 + 2 * lane; // my 2 floats in hs

    // weights pinned (atomic loads can't be rematerialized into the loop)
    float w[32];
#pragma unroll
    for (int jj = 0; jj < 8; ++jj)
#pragma unroll
        for (int i = 0; i < 4; ++i)
            w[jj * 4 + i] = __hip_atomic_load(
                &Whh[(size_t)row * HH + wave * 128 + jj * 16 + q * 4 + i],
                __ATOMIC_RELAXED, __HIP_MEMORY_SCOPE_WORKGROUP);

    const bool is_writer = (wave == 0) && (lane < RPB);
    const float bias = is_writer ? bhh[b * RPB + lane] : 0.f;

    __shared__ float hs[HH];               // staged h (fp32), wave-private
    // transposed partial buffer: part[idx][g], idx = q*16+r, g = wave.
    __shared__ __align__(16) float part[64][20];

    // R22 ring state: loop-carried so in-flight returns always land in
    // live registers (drained + consumed after the t-loop).
    unsigned int tg0 = 0, tg1 = 0, tg2 = 0;          // 4B tag samples
    unsigned long long f0 = 0, f1 = 0, f2 = 0;       // 8B full samples

    int last_c = -1;

    for (int t = 0; t < TT; ++t) {
        // xp gating + load: only writer lanes; poll only at chunk boundary
        float xpv = 0.f;
        unsigned int xv_bits = 0;
        if (is_writer) {
            const int c = t >> 6;   // t / CHUNK_T
            if (c != last_c) {
                while (__hip_atomic_load(&chunk_done[c],
                        __ATOMIC_RELAXED, __HIP_MEMORY_SCOPE_AGENT) < NHT) {}
                last_c = c;
            }
            if (t == 0) {
                xpv = __hip_atomic_load(&xp[(size_t)t * HH + b * RPB + lane],
                                        __ATOMIC_RELAXED, __HIP_MEMORY_SCOPE_AGENT);
            } else {
                // asm-issued: FIFO-oldest vs the poll ring; completed by the
                // tail's vmcnt(4) (FIFO proof in header comment). No
                // compiler vmcnt(0) drain on the tail path.
                asm volatile("global_load_dword %0, %1, off sc1"
                             : "=v"(xv_bits)
                             : "v"((unsigned long long)(uintptr_t)
                                   &xp[(size_t)t * HH + b * RPB + lane])
                             : "memory");
            }
        }

        // stage MY wave's 128-float chunk: ONE tagged word per lane
        if (t == 0) {
            float2 hv; hv.x = h0[s0]; hv.y = h0[s0 + 1];
            *(float2*)&hs[s0] = hv;
        } else {
            // R19/R20 dead-window sleep (unchanged).
            if (wave == 0) __builtin_amdgcn_s_sleep(8);    // ~512 cyc
            else           __builtin_amdgcn_s_sleep(12);   // ~768 cyc

            const unsigned int want = (unsigned int)t;
            const unsigned long long* mb = mbox + (size_t)(t & 1) * MBW;
            const unsigned long long mbaddr =
                (unsigned long long)(uintptr_t)(mb + m0);

            // ---- pipelined tag sampler: ring of 3 {tag4B, full8B} pairs,
            // issues spread ~128cyc, vmcnt(4) checks oldest pair. Exit ph =
            // matched phase, or 3 after 16 rings (fallback).
            unsigned int ph;
            int ct;
            asm volatile(
                "s_mov_b32 %[ct], 16\n\t"
                "global_load_dword   %[t0], %[ad], off offset:4 sc1\n\t"
                "global_load_dwordx2 %[f0], %[ad], off sc1\n\t"
                "s_sleep 2\n\t"
                "global_load_dword   %[t1], %[ad], off offset:4 sc1\n\t"
                "global_load_dwordx2 %[f1], %[ad], off sc1\n\t"
                "s_sleep 2\n\t"
                "global_load_dword   %[t2], %[ad], off offset:4 sc1\n\t"
                "global_load_dwordx2 %[f2], %[ad], off sc1\n\t"
                "RP%=:\n\t"
                "s_waitcnt vmcnt(4)\n\t"
                "v_cmp_ne_u32 vcc, %[wt], %[t0]\n\t"
                "s_cbranch_vccz E0%=\n\t"
                "global_load_dword   %[t0], %[ad], off offset:4 sc1\n\t"
                "global_load_dwordx2 %[f0], %[ad], off sc1\n\t"
                "s_sleep 2\n\t"
                "s_waitcnt vmcnt(4)\n\t"
                "v_cmp_ne_u32 vcc, %[wt], %[t1]\n\t"
                "s_cbranch_vccz E1%=\n\t"
                "global_load_dword   %[t1], %[ad], off offset:4 sc1\n\t"
                "global_load_dwordx2 %[f1], %[ad], off sc1\n\t"
                "s_sleep 2\n\t"
                "s_waitcnt vmcnt(4)\n\t"
                "v_cmp_ne_u32 vcc, %[wt], %[t2]\n\t"
                "s_cbranch_vccz E2%=\n\t"
                "global_load_dword   %[t2], %[ad], off offset:4 sc1\n\t"
                "global_load_dwordx2 %[f2], %[ad], off sc1\n\t"
                "s_sleep 2\n\t"
                "s_sub_i32 %[ct], %[ct], 1\n\t"
                "s_cmp_gt_i32 %[ct], 0\n\t"
                "s_cbranch_scc1 RP%=\n\t"
                "s_mov_b32 %[ph], 3\n\t"
                "s_branch EX%=\n\t"
                "E0%=:\n\t"
                "s_mov_b32 %[ph], 0\n\t"
                "s_branch EX%=\n\t"
                "E1%=:\n\t"
                "s_mov_b32 %[ph], 1\n\t"
                "s_branch EX%=\n\t"
                "E2%=:\n\t"
                "s_mov_b32 %[ph], 2\n\t"
                "EX%=:\n\t"
                : [ph] "=&s"(ph), [ct] "=&s"(ct),
                  [t0] "+v"(tg0), [t1] "+v"(tg1), [t2] "+v"(tg2),
                  [f0] "+v"(f0), [f1] "+v"(f1), [f2] "+v"(f2)
                : [ad] "v"(mbaddr), [wt] "s"(want)
                : "vcc", "memory");

            unsigned long long v;
            if (ph == 0)      v = f0;
            else if (ph == 1) v = f1;
            else if (ph == 2) v = f2;
            else              v = 0;   // miss -> guaranteed fallback below
            // correctness guard unchanged: embedded tag re-validated; the
            // atomic do-while is the authoritative path on any mismatch.
            while ((unsigned int)(v >> 32) != want)
                v = __hip_atomic_load(&mb[m0],
                        __ATOMIC_RELAXED, __HIP_MEMORY_SCOPE_AGENT);

            half2v hp = __builtin_bit_cast(half2v, (unsigned int)v);
            float2 hv;
            hv.x = (float)hp[0];
            hv.y = (float)hp[1];
            *(float2*)&hs[s0] = hv;   // same-wave write->read: lgkmcnt only
        }

        // matvec partial: 8 broadcast ds_read_b128 + 32 FMA (interleaved map)
        const float* hk = &hs[wave * 128 + q * 4];
        float p = 0.f;
#pragma unroll
        for (int jj = 0; jj < 8; ++jj) {
            float4 h4 = *(const float4*)&hk[jj * 16];
            p += w[jj * 4 + 0] * h4.x + w[jj * 4 + 1] * h4.y
               + w[jj * 4 + 2] * h4.z + w[jj * 4 + 3] * h4.w;
        }
        part[(q << 4) | r][wave] = p;     // transposed: [idx][g]
        __syncthreads();   // (B) the ONLY barrier per step

        if (wave == 0) {
            // publisher wave gets priority over the waiting waves (T5)
            __builtin_amdgcn_s_setprio(1);
            // lane l owns idx = l; sum the 16 k-chunk waves ascending.
            const float4* pr = (const float4*)&part[lane][0];
            float4 p0 = pr[0];
            float4 p1 = pr[1];
            float4 p2 = pr[2];
            float4 p3 = pr[3];
            float s = p0.x; s += p0.y; s += p0.z; s += p0.w;
            s += p1.x; s += p1.y; s += p1.z; s += p1.w;
            s += p2.x; s += p2.y; s += p2.z; s += p2.w;
            s += p3.x; s += p3.y; s += p3.z; s += p3.w;
            s += __shfl_xor(s, 16, 64);   // fold qq bit 0
            s += __shfl_xor(s, 32, 64);   // fold qq bit 1
            // xp completion: vmcnt(4) leaves the <=4 ring leftovers in
            // flight but FIFO-guarantees the older asm xp load returned.
            asm volatile("s_waitcnt vmcnt(4)" ::: "memory");
            float xq = (t == 0) ? xpv : __builtin_bit_cast(float, xv_bits);
            float z = xq + bias + s;
            z = fminf(15.f, fmaxf(-15.f, z));
            float e = __builtin_exp2f(z * 2.885390082f);
            float hvv = (e - 1.f) * __builtin_amdgcn_rcpf(e + 1.f);
            // pack rows 2i,2i+1 into lane i (i<8): one 64B-line publish FIRST
            float ha = __shfl(hvv, 2 * lane, 64);
            float hb = __shfl(hvv, 2 * lane + 1, 64);
            if (lane < 8) {
                half2v pk2 = __builtin_amdgcn_cvt_pkrtz(ha, hb);
                unsigned int pb = __builtin_bit_cast(unsigned int, pk2);
                unsigned long long word =
                    ((unsigned long long)(unsigned int)(t + 1) << 32) |
                    (unsigned long long)pb;
                __hip_atomic_store(&mbox[(size_t)((t + 1) & 1) * MBW + b * 8 + lane],
                                   word, __ATOMIC_RELAXED, __HIP_MEMORY_SCOPE_AGENT);
            }
            __builtin_amdgcn_s_setprio(0);
            if (lane < RPB)
                outs[(size_t)t * HH + b * RPB + lane] = hvv;  // plain cached
        }
        // part overwrite for t+1 gated by wave w's next poll, which
        // requires this block's wave-0 publish (after the reads above).
    }

    // drain ring leftovers before endpgm; keep ring regs live to here so
    // late returns always land in reserved registers.
    asm volatile("s_waitcnt vmcnt(0)" ::: "memory");
    asm volatile("" :: "v"(tg0), "v"(tg1), "v"(tg2),
                       "v"(f0), "v"(f1), "v"(f2));
}

// ---------------------------------------------------------------------------
extern "C" void kernel_launch(void* const* d_in, const int* in_sizes, int n_in,
                              void* d_out, int out_size, void* d_ws, size_t ws_size,
                              hipStream_t stream)
{
    const float* x     = (const float*)d_in[0];  // (T,1,H)
    const float* W_ih  = (const float*)d_in[1];  // (H,H)
    const float* W_hh  = (const float*)d_in[2];  // (H,H)
    const float* b_ih  = (const float*)d_in[3];  // (H)
    const float* b_hh  = (const float*)d_in[4];  // (H)
    const float* W_lin = (const float*)d_in[5];  // (O,H)
    const float* b_lin = (const float*)d_in[6];  // (O)
    const float* h0    = (const float*)d_in[7];  // (1,1,H)
    float* out = (float*)d_out;                  // (T,1,O)

    char* ws = (char*)d_ws;
    float* xp    = (float*)ws;                                       // 32 MB
    float* outs  = (float*)(ws + (size_t)TT * HH * 4);               // 32 MB
    unsigned long long* mbox =
        (unsigned long long*)(ws + 2 * (size_t)TT * HH * 4);         // 16 KB
    int* chunk_done =
        (int*)(ws + 2 * (size_t)TT * HH * 4 + 2 * MBW * 8);          // 256 B

    // chunk counters must start at 0 (ws arrives poisoned); mailbox needs
    // no init (t==0 reads h0; poisoned tag never equals a wanted tag).
    hipMemsetAsync(chunk_done, 0, NCHUNK * sizeof(int), stream);

    // Fused phase 1 + phase 2: scan blocks 0..127, xp workers 128..255
    rnn_fused<<<2 * NB, 1024, 0, stream>>>(
        x, W_ih, b_ih, W_hh, b_hh, h0, xp, outs, mbox, chunk_done);

    // Phase 3: out = outs @ W_lin^T + b_lin (512 blocks, 2/CU)
    gemm_nt_bias64<<<dim3(TT / 64, OO / 64), 256, 0, stream>>>(
        outs, W_lin, b_lin, out, TT, OO, HH);
}

// Round 8
// 6092.817 us; speedup vs baseline: 1.3435x; 1.3435x over previous
//
#include <hip/hip_runtime.h>
#include <math.h>

// Problem constants (Elman RNN)
#define TT 4096
#define HH 2048
#define OO 512

#define NB  128    // scan blocks
#define RPB 16     // rows per block = HH/NB
#define MBW (HH/2) // mailbox words per buffer (fp16 x2 per word)

#define CHUNK_T 64             // t-rows per xp chunk
#define NCHUNK  (TT/CHUNK_T)   // 64 chunks
#define HTILE   128
#define NHT     (HH/HTILE)     // 16 h-tiles per chunk

typedef __fp16 half2v __attribute__((ext_vector_type(2)));

// ---------------------------------------------------------------------------
// Trailing phase 3: fp32 NT GEMM  C[m,n] = sum_k A[m,k]*B[n,k] + bias[n]
// R15: 64x64 tiles -> grid 64x8 = 512 blocks = 2 blocks/CU = 2 waves/SIMD
// 256 threads, 4x4 acc/thread, BK=8, float2 staging, float4 broadcast reads.
// ---------------------------------------------------------------------------
__global__ __launch_bounds__(256) void gemm_nt_bias64(
    const float* __restrict__ A, const float* __restrict__ B,
    const float* __restrict__ bias, float* __restrict__ C,
    int M, int N, int K)
{
    __shared__ float As[8][72];
    __shared__ float Bs[8][72];

    const int tid = threadIdx.x;
    const int bm = blockIdx.x * 64;
    const int bn = blockIdx.y * 64;

    // staging: 64 rows x 8 k = 512 floats each => float2 per thread
    const int srow = tid >> 2;          // 0..63
    const int skk  = (tid & 3) * 2;     // 0,2,4,6

    const int ty = tid >> 4;            // 0..15 -> rows ty*4..ty*4+3
    const int tx = tid & 15;            // 0..15 -> cols tx*4..tx*4+3

    float acc[4][4];
#pragma unroll
    for (int i = 0; i < 4; i++)
#pragma unroll
        for (int j = 0; j < 4; j++) acc[i][j] = 0.f;

    for (int k0 = 0; k0 < K; k0 += 8) {
        float2 av = *(const float2*)&A[(size_t)(bm + srow) * K + k0 + skk];
        float2 bv = *(const float2*)&B[(size_t)(bn + srow) * K + k0 + skk];
        __syncthreads();
        As[skk][srow]     = av.x;
        As[skk + 1][srow] = av.y;
        Bs[skk][srow]     = bv.x;
        Bs[skk + 1][srow] = bv.y;
        __syncthreads();
#pragma unroll
        for (int kk = 0; kk < 8; kk++) {
            float4 a4 = *(const float4*)&As[kk][ty * 4];
            float4 b4 = *(const float4*)&Bs[kk][tx * 4];
            float a[4] = {a4.x, a4.y, a4.z, a4.w};
            float b[4] = {b4.x, b4.y, b4.z, b4.w};
#pragma unroll
            for (int i = 0; i < 4; i++)
#pragma unroll
                for (int j = 0; j < 4; j++)
                    acc[i][j] += a[i] * b[j];
        }
    }

    {
        const int n = bn + tx * 4;
        float4 bv = *(const float4*)&bias[n];
#pragma unroll
        for (int i = 0; i < 4; i++) {
            const int m = bm + ty * 4 + i;
            float4 cv;
            cv.x = acc[i][0] + bv.x;
            cv.y = acc[i][1] + bv.y;
            cv.z = acc[i][2] + bv.z;
            cv.w = acc[i][3] + bv.w;
            *(float4*)&C[(size_t)m * N + n] = cv;
        }
    }
}

// ---------------------------------------------------------------------------
// R23 = R20 restored byte-identical (verified best: rnn_fused ~6031 us).
// Ledger of probed levers (all within-session A/B):
//   tail slim (R16)        -43 cyc/step   | keep
//   packed-fp16 LDS (R17)  +50            | reverted
//   tag-summary gate (R18) +1090          | reverted (1 MALL hop ~ 1000 cyc)
//   dead-window sleep (R19/R20) -535      | keep (12/8, at arrival edge)
//   64x32 topology (R21)   +640           | reverted
//   pipelined sampler (R22)+820           | reverted (poll density trades
//                                           against fabric contention; the
//                                           1-outstanding do-while is at the
//                                           contention-optimal density)
// Remaining step ~3530 cyc = store->MALL visibility + contention-optimal
// discovery + max-over-128 jitter + compute chain: the agent-scope-RT x
// serial-dependency floor for this chip (no faster inter-CU channel:
// LDS is CU-local, per-XCD L2 non-coherent, no clusters/DSMEM).
// Iron rule (R2/R12/R13): during the live exchange every other CU must be
// DEAD. A sleeping scan wave issues no memory ops -- strictly less fabric
// pressure than a polling one.
// Gating invariant: wave0's mailbox publish of step t data-depends on ALL
// 16 partials of step t; other blocks' t+1 publishes (hence this block's
// own t+1 partial writes) are transitively gated behind it, which makes
// the partial-buffer overwrite safe.
// ---------------------------------------------------------------------------
__global__ __launch_bounds__(1024) void rnn_fused(
    const float* __restrict__ x,     // (T,H) input
    const float* __restrict__ Wih,   // (H,H)
    const float* __restrict__ bih,   // (H)
    const float* __restrict__ Whh,   // (H,H)
    const float* __restrict__ bhh,   // (H)
    const float* __restrict__ h0,    // (H)
    float* __restrict__ xp,          // (T,H) ws: input projection
    float* __restrict__ outs,        // (T,H) ws: hidden states
    unsigned long long* __restrict__ mbox,  // [2][MBW] tagged fp16x2 mailbox
    int* __restrict__ chunk_done)    // [NCHUNK] xp-chunk arm counters
{
    const int tid = threadIdx.x;     // 0..1023

    if (blockIdx.x >= NB) {
        // ------------------- xp GEMM worker (exact R10) -------------------
        __shared__ float As[16][65];     // [kk][t-row], padded
        __shared__ float Bs[16][132];    // [kk][h-col], padded+aligned

        const int w2   = blockIdx.x - NB;   // 0..127
        const int ty   = tid >> 5;          // 0..31 -> t-rows ty*2, ty*2+1
        const int tx   = tid & 31;          // 0..31 -> h-cols tx*4..
        const int arow = tid >> 4;          // 0..63
        const int akk  = tid & 15;
        const int bcol = tid >> 3;          // 0..127
        const int bkk  = (tid & 7) * 2;

        for (int round = 0; round < (NCHUNK * NHT) / 128; ++round) {
            const int tile  = w2 + 128 * round;   // t-major: early t first
            const int chunk = tile >> 4;
            const int htile = tile & 15;
            const int bm = chunk * CHUNK_T;
            const int bn = htile * HTILE;

            float acc[2][4];
#pragma unroll
            for (int i = 0; i < 2; ++i)
#pragma unroll
                for (int j = 0; j < 4; ++j) acc[i][j] = 0.f;

            for (int k0 = 0; k0 < HH; k0 += 16) {
                float  av = x[(size_t)(bm + arow) * HH + k0 + akk];
                float2 bv = *(const float2*)&Wih[(size_t)(bn + bcol) * HH + k0 + bkk];
                __syncthreads();
                As[akk][arow]     = av;
                Bs[bkk][bcol]     = bv.x;
                Bs[bkk + 1][bcol] = bv.y;
                __syncthreads();
#pragma unroll
                for (int kk = 0; kk < 16; ++kk) {
                    float a0 = As[kk][ty * 2];
                    float a1 = As[kk][ty * 2 + 1];
                    float b0 = Bs[kk][tx * 4 + 0];
                    float b1 = Bs[kk][tx * 4 + 1];
                    float b2 = Bs[kk][tx * 4 + 2];
                    float b3 = Bs[kk][tx * 4 + 3];
                    acc[0][0] += a0 * b0; acc[0][1] += a0 * b1;
                    acc[0][2] += a0 * b2; acc[0][3] += a0 * b3;
                    acc[1][0] += a1 * b0; acc[1][1] += a1 * b1;
                    acc[1][2] += a1 * b2; acc[1][3] += a1 * b3;
                }
            }
#pragma unroll
            for (int i = 0; i < 2; ++i) {
                const int m = bm + ty * 2 + i;
#pragma unroll
                for (int j = 0; j < 4; ++j) {
                    const int n = bn + tx * 4 + j;
                    __hip_atomic_store(&xp[(size_t)m * HH + n],
                                       acc[i][j] + bih[n],
                                       __ATOMIC_RELAXED, __HIP_MEMORY_SCOPE_AGENT);
                }
            }
            __syncthreads();   // all waves' stores retired first
            if (tid == 0)
                __hip_atomic_fetch_add(&chunk_done[chunk], 1,
                                       __ATOMIC_RELEASE, __HIP_MEMORY_SCOPE_AGENT);
        }
        return;   // workers DIE here -- CUs go fully idle for the scan
    }

    // ---------------- scan (R16 core + R20 edge-tuned sleep) ---------------
    const int b    = blockIdx.x;     // 0..127
    const int wave = tid >> 6;       // 0..15
    const int lane = tid & 63;
    const int r    = lane & 15;      // local row 0..15
    const int q    = lane >> 4;      // 0..3: interleaved 4-float subchunk
    const int row  = b * RPB + r;    // global row this thread accumulates
    const int m0   = wave * 64 + lane;      // my mailbox word (covers 2 rows)
    const int s0   = wave * 128 + 2 * lane; // my 2 floats in hs

    // weights pinned (atomic loads can't be rematerialized into the loop)
    float w[32];
#pragma unroll
    for (int jj = 0; jj < 8; ++jj)
#pragma unroll
        for (int i = 0; i < 4; ++i)
            w[jj * 4 + i] = __hip_atomic_load(
                &Whh[(size_t)row * HH + wave * 128 + jj * 16 + q * 4 + i],
                __ATOMIC_RELAXED, __HIP_MEMORY_SCOPE_WORKGROUP);

    const bool is_writer = (wave == 0) && (lane < RPB);
    const float bias = is_writer ? bhh[b * RPB + lane] : 0.f;

    __shared__ float hs[HH];               // staged h (fp32), wave-private
    // R16 transposed partial buffer: part[idx][g], idx = q*16+r, g = wave.
    __shared__ __align__(16) float part[64][20];

    int last_c = -1;

    for (int t = 0; t < TT; ++t) {
        // xp gating + load: only writer lanes; poll only at chunk boundary
        float xpv = 0.f;
        if (is_writer) {
            const int c = t >> 6;   // t / CHUNK_T
            if (c != last_c) {
                while (__hip_atomic_load(&chunk_done[c],
                        __ATOMIC_RELAXED, __HIP_MEMORY_SCOPE_AGENT) < NHT) {}
                last_c = c;
            }
            xpv = __hip_atomic_load(&xp[(size_t)t * HH + b * RPB + lane],
                                    __ATOMIC_RELAXED, __HIP_MEMORY_SCOPE_AGENT);
        }

        // stage MY wave's 128-float chunk: ONE tagged word per lane
        if (t == 0) {
            float2 hv; hv.x = h0[s0]; hv.y = h0[s0 + 1];
            *(float2*)&hs[s0] = hv;
        } else {
            // R20: sleep through the provably-dead window before touching
            // the fabric. Arrival ~ tau+850-1000; waves 1..15 wake at
            // tau+768, wave0 at ~tau+760 absolute (250 tail + 512 sleep).
            if (wave == 0) __builtin_amdgcn_s_sleep(8);    // ~512 cyc
            else           __builtin_amdgcn_s_sleep(12);   // ~768 cyc
            const unsigned int want = (unsigned int)t;
            const unsigned long long* mb = mbox + (size_t)(t & 1) * MBW;
            unsigned long long v;
            do {
                v = __hip_atomic_load(&mb[m0],
                    __ATOMIC_RELAXED, __HIP_MEMORY_SCOPE_AGENT);
            } while ((unsigned int)(v >> 32) != want);
            half2v hp = __builtin_bit_cast(half2v, (unsigned int)v);
            float2 hv;
            hv.x = (float)hp[0];
            hv.y = (float)hp[1];
            *(float2*)&hs[s0] = hv;   // same-wave write->read: lgkmcnt only
        }

        // matvec partial: 8 broadcast ds_read_b128 + 32 FMA (interleaved map)
        const float* hk = &hs[wave * 128 + q * 4];
        float p = 0.f;
#pragma unroll
        for (int jj = 0; jj < 8; ++jj) {
            float4 h4 = *(const float4*)&hk[jj * 16];
            p += w[jj * 4 + 0] * h4.x + w[jj * 4 + 1] * h4.y
               + w[jj * 4 + 2] * h4.z + w[jj * 4 + 3] * h4.w;
        }
        part[(q << 4) | r][wave] = p;     // transposed: [idx][g]
        __syncthreads();   // (B) the ONLY barrier per step

        if (wave == 0) {
            // publisher wave gets priority over the waiting waves (T5)
            __builtin_amdgcn_s_setprio(1);
            // lane l owns idx = l = (q<<4)|r; sum the 16 k-chunk waves in
            // ascending g order via 4x ds_read_b128.
            const float4* pr = (const float4*)&part[lane][0];
            float4 p0 = pr[0];
            float4 p1 = pr[1];
            float4 p2 = pr[2];
            float4 p3 = pr[3];
            float s = p0.x; s += p0.y; s += p0.z; s += p0.w;
            s += p1.x; s += p1.y; s += p1.z; s += p1.w;
            s += p2.x; s += p2.y; s += p2.z; s += p2.w;
            s += p3.x; s += p3.y; s += p3.z; s += p3.w;
            s += __shfl_xor(s, 16, 64);   // fold qq bit 0
            s += __shfl_xor(s, 32, 64);   // fold qq bit 1
            float z = xpv + bias + s;
            z = fminf(15.f, fmaxf(-15.f, z));
            float e = __builtin_exp2f(z * 2.885390082f);
            float hv = (e - 1.f) * __builtin_amdgcn_rcpf(e + 1.f);
            // pack rows 2i,2i+1 into lane i (i<8): one 64B-line publish FIRST
            float ha = __shfl(hv, 2 * lane, 64);
            float hb = __shfl(hv, 2 * lane + 1, 64);
            if (lane < 8) {
                half2v pk2 = __builtin_amdgcn_cvt_pkrtz(ha, hb);
                unsigned int pb = __builtin_bit_cast(unsigned int, pk2);
                unsigned long long word =
                    ((unsigned long long)(unsigned int)(t + 1) << 32) |
                    (unsigned long long)pb;
                __hip_atomic_store(&mbox[(size_t)((t + 1) & 1) * MBW + b * 8 + lane],
                                   word, __ATOMIC_RELAXED, __HIP_MEMORY_SCOPE_AGENT);
            }
            __builtin_amdgcn_s_setprio(0);
            if (lane < RPB)
                outs[(size_t)t * HH + b * RPB + lane] = hv;  // plain cached
        }
        // part overwrite for t+1 gated by wave w's next poll, which
        // requires this block's wave-0 publish (after the reads above).
    }
}

// ---------------------------------------------------------------------------
extern "C" void kernel_launch(void* const* d_in, const int* in_sizes, int n_in,
                              void* d_out, int out_size, void* d_ws, size_t ws_size,
                              hipStream_t stream)
{
    const float* x     = (const float*)d_in[0];  // (T,1,H)
    const float* W_ih  = (const float*)d_in[1];  // (H,H)
    const float* W_hh  = (const float*)d_in[2];  // (H,H)
    const float* b_ih  = (const float*)d_in[3];  // (H)
    const float* b_hh  = (const float*)d_in[4];  // (H)
    const float* W_lin = (const float*)d_in[5];  // (O,H)
    const float* b_lin = (const float*)d_in[6];  // (O)
    const float* h0    = (const float*)d_in[7];  // (1,1,H)
    float* out = (float*)d_out;                  // (T,1,O)

    char* ws = (char*)d_ws;
    float* xp    = (float*)ws;                                       // 32 MB
    float* outs  = (float*)(ws + (size_t)TT * HH * 4);               // 32 MB
    unsigned long long* mbox =
        (unsigned long long*)(ws + 2 * (size_t)TT * HH * 4);         // 16 KB
    int* chunk_done =
        (int*)(ws + 2 * (size_t)TT * HH * 4 + 2 * MBW * 8);          // 256 B

    // chunk counters must start at 0 (ws arrives poisoned); mailbox needs
    // no init (t==0 reads h0; poisoned tag never equals a wanted tag).
    hipMemsetAsync(chunk_done, 0, NCHUNK * sizeof(int), stream);

    // Fused phase 1 + phase 2: scan blocks 0..127, xp workers 128..255
    rnn_fused<<<2 * NB, 1024, 0, stream>>>(
        x, W_ih, b_ih, W_hh, b_hh, h0, xp, outs, mbox, chunk_done);

    // Phase 3: out = outs @ W_lin^T + b_lin (512 blocks, 2/CU)
    gemm_nt_bias64<<<dim3(TT / 64, OO / 64), 256, 0, stream>>>(
        outs, W_lin, b_lin, out, TT, OO, HH);
}